// Round 9
// baseline (319.536 us; speedup 1.0000x reference)
//
#include <hip/hip_runtime.h>
#include <stdint.h>

// Depthwise causal conv via MFMA Toeplitz, f16 single-chain:
//   y[p, q0+16t+j] = sum_r sum_k x[p+r-5, q0+16t-8+k] * B_r[k,j],
//   B_r[k,j] = w[r, k-j-3] for k-j-3 in [0,10], else 0.
// f16 (10-bit mantissa): predicted absmax ~2e-3 vs threshold 0.104 -> no
// hi/lo compensation needed. N=2, C=16, H=W=2048. Block = 4 waves = 64x64.

#define HDIM 2048
#define WDIM 2048
#define CH   16

#define PITCH 88            // LDS row pitch in f16 (176B): uniform 8/bank b128
#define XROWS 69            // 64 + 5 halo rows
#define NSL   (XROWS * 20)  // staging slots (float4 granules): 1380

typedef float    f32x4 __attribute__((ext_vector_type(4)));
typedef _Float16 f16x8 __attribute__((ext_vector_type(8)));
typedef _Float16 f16x4 __attribute__((ext_vector_type(4)));

__global__ __launch_bounds__(256, 8)
void dwconv_mfma(const float* __restrict__ x, const float* __restrict__ wgt,
                 float* __restrict__ out) {
  const int bx = blockIdx.x, by = blockIdx.y, plane = blockIdx.z;
  const int q0 = bx * 64, p0 = by * 64;
  const int tid = threadIdx.x;
  const size_t pb = (size_t)plane * HDIM * WDIM;
  const float* __restrict__ xp = x + pb;
  float* __restrict__ op = out + pb;

  // Strictly-upper block: zeros only.
  if (p0 + 63 < q0) {
    const float4 z = make_float4(0.f, 0.f, 0.f, 0.f);
#pragma unroll
    for (int i = 0; i < 4; ++i) {  // 64 rows x 16 float4
      int idx = i * 256 + tid;
      int row = idx >> 4, c4 = idx & 15;
      *(float4*)(op + (size_t)(p0 + row) * WDIM + q0 + 4 * c4) = z;
    }
    return;
  }

  __shared__ _Float16 s_x[XROWS * PITCH];  // 12144 B -> 8 blocks/CU (wave cap)

  // ---- Stage x tile as f16 (causal + bounds mask folded in) ----
  // pure: rows [p0-5,p0+63], cols [q0-8,q0+71] all in-bounds AND causal.
  const bool pure = (bx >= 1) && (bx <= 30) && (p0 >= q0 + 76);
#pragma unroll
  for (int j = 0; j < 6; ++j) {
    int slot = j * 256 + tid;
    if (slot < NSL) {
      int row = slot / 20;
      int c4 = slot - row * 20;
      int ih = p0 - 5 + row;
      int cb = q0 - 8 + 4 * c4;
      float4 v = make_float4(0.f, 0.f, 0.f, 0.f);
      if (pure) {
        v = *(const float4*)(xp + (size_t)ih * WDIM + cb);
      } else if (ih >= 0) {  // ih <= p0+63 <= 2047 always
        bool fullv = (cb >= 0) && (cb + 3 <= ih) && (cb + 3 < WDIM);
        if (fullv) {
          v = *(const float4*)(xp + (size_t)ih * WDIM + cb);
        } else {
          float* vv = &v.x;
#pragma unroll
          for (int e = 0; e < 4; ++e) {
            int iw = cb + e;
            if (iw >= 0 && iw < WDIM && iw <= ih)
              vv[e] = xp[(size_t)ih * WDIM + iw];
          }
        }
      }
      f16x4 h4;
      h4[0] = (_Float16)v.x; h4[1] = (_Float16)v.y;
      h4[2] = (_Float16)v.z; h4[3] = (_Float16)v.w;
      *(f16x4*)&s_x[row * PITCH + 4 * c4] = h4;
    }
  }

  // ---- Build 6 Toeplitz B-fragments (one per tap row r) ----
  // B layout: lane holds B[k = 8*(lane>>4)+i, j = lane&15], i=0..7.
  const int lane = tid & 63;
  const int j16 = lane & 15;
  const int wk = lane >> 4;
  const float* __restrict__ wcp = wgt + (plane & (CH - 1)) * 66;
  f16x8 bw[6];
#pragma unroll
  for (int r = 0; r < 6; ++r) {
#pragma unroll
    for (int i = 0; i < 8; ++i) {
      int k = 8 * wk + i;
      int d = k - j16 - 3;  // tap index s
      bw[r][i] = (_Float16)((d >= 0 && d <= 10) ? wcp[r * 11 + d] : 0.f);
    }
  }

  __syncthreads();

  // ---- 4 waves x (4 col-tiles x 6 r) MFMAs, single f16 chain ----
  const int wid = tid >> 6;  // wave's 16-row output strip
  f32x4 acc[4];
#pragma unroll
  for (int t = 0; t < 4; ++t) acc[t] = (f32x4){0.f, 0.f, 0.f, 0.f};

#pragma unroll
  for (int t = 0; t < 4; ++t) {
#pragma unroll
    for (int r = 0; r < 6; ++r) {
      // A layout: lane holds A[m = lane&15, k = 8*(lane>>4)+i];
      // A[m,k] = x_tile[16*wid + m + r, 16t + k]  (LDS cols rel q0-8).
      int off = (16 * wid + j16 + r) * PITCH + 16 * t + 8 * wk;
      f16x8 ah = *(const f16x8*)&s_x[off];
      acc[t] = __builtin_amdgcn_mfma_f32_16x16x32_f16(ah, bw[r], acc[t], 0, 0, 0);
    }
  }

  // ---- Store: D layout col = lane&15, row = 4*(lane>>4)+reg ----
  const bool needmask = (q0 + 63 > p0);
#pragma unroll
  for (int t = 0; t < 4; ++t) {
    const int q = q0 + 16 * t + j16;
#pragma unroll
    for (int reg = 0; reg < 4; ++reg) {
      const int p = p0 + 16 * wid + 4 * wk + reg;
      float val = acc[t][reg];
      if (needmask && q > p) val = 0.f;
      op[(size_t)p * WDIM + q] = val;
    }
  }
}

extern "C" void kernel_launch(void* const* d_in, const int* in_sizes, int n_in,
                              void* d_out, int out_size, void* d_ws, size_t ws_size,
                              hipStream_t stream) {
  const float* x   = (const float*)d_in[0];
  const float* wgt = (const float*)d_in[1];
  float* out       = (float*)d_out;
  dim3 grid(WDIM / 64, HDIM / 64, 2 * CH);  // (32, 32, 32)
  dwconv_mfma<<<grid, dim3(256), 0, stream>>>(x, wgt, out);
}